// Round 12
// baseline (541.896 us; speedup 1.0000x reference)
//
#include <hip/hip_runtime.h>

// Fused 4-layer RNN (LSTM,LSTM,GRU,GRU, H=64) + FC head. B=2048, T=512.
// ELASTIC layer pipeline, flag-based sync: 256 blocks x 1024 threads
// (16 waves). Layer L owns waves [4L,4L+4); each wave owns a 16-dim
// h-chunk. 8 batch rows/block at A-rows {0,1,4,5,8,9,12,13}. Each stream
// is a 4-deep LDS ring. R12: per-wave flags flg[L][wv]=t+1 (plain stores,
// no atomic RMW serialization); consumer spins on min(4 flags) >= tgt.
// Ticks reordered: upstream spin + upstream reads + x-part MFMAs happen
// BEFORE the own-group spin -> only h-part MFMA + elementwise on the
// post-spin critical path. Bias folded into MFMA C operand; weights
// pre-scaled by -log2e / -2log2e (exp2-native activations).

#define TT 512
#define SR 72            // state row stride (shorts)
#define SLOT (16 * SR)   // one ring slot (shorts)
#define LOG2E 1.44269504f

typedef __attribute__((ext_vector_type(8))) short bfrag;  // 8 bf16
typedef __attribute__((ext_vector_type(4))) float facc;   // 4 f32

#define MFMA(a,b,c) __builtin_amdgcn_mfma_f32_16x16x32_bf16((a),(b),(c),0,0,0)

// u already scaled by -log2e: sigma(x) = 1/(1+2^u)
__device__ __forceinline__ float sigmP(float u){
  return __builtin_amdgcn_rcpf(1.0f + __builtin_amdgcn_exp2f(u));
}
// u already scaled by -2*log2e: tanh(x) = 2/(1+2^u) - 1
__device__ __forceinline__ float tanhP(float u){
  return 2.0f * __builtin_amdgcn_rcpf(1.0f + __builtin_amdgcn_exp2f(u)) - 1.0f;
}
// wait until all 4 per-wave flags of a group reach tgt
__device__ __forceinline__ void spin_grp(volatile int* f, int tgt){
  for (;;) {
    const int a = f[0], b = f[1], c = f[2], d = f[3];
    const int m0 = a < b ? a : b;
    const int m1 = c < d ? c : d;
    if ((m0 < m1 ? m0 : m1) >= tgt) return;
  }
}
__device__ __forceinline__ facc bcast4(float v){
  facc b; b[0] = v; b[1] = v; b[2] = v; b[3] = v; return b;
}
__device__ __forceinline__ short f2bf(float f){
  union { float f; unsigned u; } v; v.f = f;
  return (short)((v.u + 0x7fffu + ((v.u >> 16) & 1u)) >> 16);  // RNE
}
// pack two f32 -> two bf16 (RNE) in one instruction
__device__ __forceinline__ unsigned pk_bf16(float lo, float hi){
  unsigned r;
  asm("v_cvt_pk_bf16_f32 %0, %1, %2" : "=v"(r) : "v"(lo), "v"(hi));
  return r;
}

__global__ __launch_bounds__(1024) void rnn_fused(
    const float* __restrict__ x,
    const float* __restrict__ lw_ih0, const float* __restrict__ lw_hh0,
    const float* __restrict__ lb_ih0, const float* __restrict__ lb_hh0,
    const float* __restrict__ lw_ih1, const float* __restrict__ lw_hh1,
    const float* __restrict__ lb_ih1, const float* __restrict__ lb_hh1,
    const float* __restrict__ gw_ih0, const float* __restrict__ gw_hh0,
    const float* __restrict__ gb_ih0, const float* __restrict__ gb_hh0,
    const float* __restrict__ gw_ih1, const float* __restrict__ gw_hh1,
    const float* __restrict__ gb_ih1, const float* __restrict__ gb_hh1,
    const float* __restrict__ fc_w, const float* __restrict__ fc_b,
    float* __restrict__ out)
{
  __shared__ __align__(16) short S0[4 * SLOT];  // h0 ring
  __shared__ __align__(16) short S1[4 * SLOT];  // h1 ring
  __shared__ __align__(16) short S2[4 * SLOT];  // h2 ring
  __shared__ __align__(16) short S3[4 * SLOT];  // h3 ring
  __shared__ float xs[8][TT];                   // full x for our 8 rows
  __shared__ float hfin[8][68];
  __shared__ int flg[4][4];                     // per-layer, per-wave: t+1

  const int tid = threadIdx.x;
  const int w     = tid >> 6;      // wave 0..15
  const int layer = w >> 2;        // 0..3
  const int lo4   = w & 3;         // h-chunk [lo4*16, lo4*16+16)
  const int l   = tid & 63;
  const int lq  = l >> 4;          // lane owns batch rows 2lq, 2lq+1
  const int lc  = l & 15;
  const int kb  = lq * 8;
  const int rb0 = blockIdx.x * 8;
  const int wrbase = (4 * lq) * SR + lo4 * 16 + lc;   // + m*SR
  volatile int* F0 = flg[0];
  volatile int* F1 = flg[1];
  volatile int* F2 = flg[2];
  volatile int* F3 = flg[3];

  const float SS  = -LOG2E;          // sigmoid-gate scale
  const float ST2 = -2.0f * LOG2E;   // tanh-gate scale

  // preload all 512 timesteps of x for our 8 rows (4096 floats, 4/thread)
  {
    const int idx = tid * 4;
    const int row = idx >> 9, t0 = idx & 511;
    *(float4*)&xs[row][t0] = *(const float4*)(x + (rb0 + row) * TT + t0);
  }
  for (int i = tid; i < 4 * SLOT; i += 1024) {
    S0[i] = 0; S1[i] = 0; S2[i] = 0; S3[i] = 0;
  }
  if (tid < 16) flg[tid >> 2][tid & 3] = 0;
  __syncthreads();

  if (layer == 0) {
    // ============ LSTM0: K=64 (h-part; x is scalar FMA) ============
    bfrag wf[4][2];
    float wxs[4];
    facc b4[4];
    #pragma unroll
    for (int G = 0; G < 4; ++G) {
      const float sc = (G == 2) ? ST2 : SS;
      const int col = G * 64 + lo4 * 16 + lc;
      #pragma unroll
      for (int kt = 0; kt < 2; ++kt) {
        bfrag f;
        #pragma unroll
        for (int j = 0; j < 8; ++j)
          f[j] = f2bf(sc * lw_hh0[col * 64 + kt * 32 + kb + j]);
        wf[G][kt] = f;
      }
      wxs[G] = sc * lw_ih0[col];
      b4[G]  = bcast4(sc * (lb_ih0[col] + lb_hh0[col]));
    }
    float c0[2] = {0.f, 0.f};
    for (int tb = 0; tb < TT / 4; ++tb) {
      const float4 xv0 = *(const float4*)&xs[2 * lq][tb * 4];
      const float4 xv1 = *(const float4*)&xs[2 * lq + 1][tb * 4];
      const float* xp0 = (const float*)&xv0;
      const float* xp1 = (const float*)&xv1;
      #pragma unroll
      for (int u = 0; u < 4; ++u) {
        const int t = tb * 4 + u;
        if (tb >= 1) spin_grp(F1, t - 3);            // LSTM1 freed slot
        if (tb > 0 || u > 0) spin_grp(F0, t);        // own group done t-1
        const short* s = S0 + ((u + 3) & 3) * SLOT;
        const bfrag a0 = *(const bfrag*)(s + lc * SR + kb);
        const bfrag a1 = *(const bfrag*)(s + lc * SR + 32 + kb);
        facc acc[4];
        #pragma unroll
        for (int G = 0; G < 4; ++G) {
          facc z = MFMA(a0, wf[G][0], b4[G]);
          z = MFMA(a1, wf[G][1], z);
          acc[G] = z;
        }
        float hh[2];
        #pragma unroll
        for (int m = 0; m < 2; ++m) {
          const float xv = m ? xp1[u] : xp0[u];
          const float i_ = sigmP(acc[0][m] + xv * wxs[0]);
          const float f_ = sigmP(acc[1][m] + xv * wxs[1]);
          const float g_ = tanhP(acc[2][m] + xv * wxs[2]);
          const float o_ = sigmP(acc[3][m] + xv * wxs[3]);
          c0[m] = f_ * c0[m] + i_ * g_;
          hh[m] = o_ * tanhP(c0[m] * ST2);
        }
        const unsigned pk = pk_bf16(hh[0], hh[1]);
        short* d = S0 + u * SLOT;
        d[wrbase]      = (short)pk;
        d[wrbase + SR] = (short)(pk >> 16);
        __threadfence_block();
        if (l == 0) F0[lo4] = t + 1;                 // release
      }
    }
  } else if (layer == 1) {
    // ============ LSTM1: K=128 ([h0_t | h1_{t-1}]) ============
    bfrag wxf[4][2], whf[4][2];
    facc b4[4];
    #pragma unroll
    for (int G = 0; G < 4; ++G) {
      const float sc = (G == 2) ? ST2 : SS;
      const int col = G * 64 + lo4 * 16 + lc;
      #pragma unroll
      for (int kt = 0; kt < 2; ++kt) {
        bfrag f0, f1;
        #pragma unroll
        for (int j = 0; j < 8; ++j) {
          const int o = col * 64 + kt * 32 + kb + j;
          f0[j] = f2bf(sc * lw_ih1[o]);
          f1[j] = f2bf(sc * lw_hh1[o]);
        }
        wxf[G][kt] = f0; whf[G][kt] = f1;
      }
      b4[G] = bcast4(sc * (lb_ih1[col] + lb_hh1[col]));
    }
    float c1[2] = {0.f, 0.f};
    for (int tb = 0; tb < TT / 4; ++tb) {
      #pragma unroll
      for (int u = 0; u < 4; ++u) {
        const int t = tb * 4 + u;
        spin_grp(F0, t + 1);                         // h0[t] ready (early)
        const short* sx = S0 + u * SLOT;
        const bfrag ax0 = *(const bfrag*)(sx + lc * SR + kb);
        const bfrag ax1 = *(const bfrag*)(sx + lc * SR + 32 + kb);
        facc acc[4];
        #pragma unroll
        for (int G = 0; G < 4; ++G) {                // x-part off critical path
          facc z = MFMA(ax0, wxf[G][0], b4[G]);
          z = MFMA(ax1, wxf[G][1], z);
          acc[G] = z;
        }
        if (tb >= 1) spin_grp(F2, t - 3);            // GRU0 freed slot
        if (tb > 0 || u > 0) spin_grp(F1, t);        // own group done t-1
        const short* sh = S1 + ((u + 3) & 3) * SLOT;
        const bfrag ah0 = *(const bfrag*)(sh + lc * SR + kb);
        const bfrag ah1 = *(const bfrag*)(sh + lc * SR + 32 + kb);
        #pragma unroll
        for (int G = 0; G < 4; ++G) {
          acc[G] = MFMA(ah0, whf[G][0], acc[G]);
          acc[G] = MFMA(ah1, whf[G][1], acc[G]);
        }
        float hh[2];
        #pragma unroll
        for (int m = 0; m < 2; ++m) {
          const float i_ = sigmP(acc[0][m]);
          const float f_ = sigmP(acc[1][m]);
          const float g_ = tanhP(acc[2][m]);
          const float o_ = sigmP(acc[3][m]);
          c1[m] = f_ * c1[m] + i_ * g_;
          hh[m] = o_ * tanhP(c1[m] * ST2);
        }
        const unsigned pk = pk_bf16(hh[0], hh[1]);
        short* d = S1 + u * SLOT;
        d[wrbase]      = (short)pk;
        d[wrbase + SR] = (short)(pk >> 16);
        __threadfence_block();
        if (l == 0) F1[lo4] = t + 1;
      }
    }
  } else if (layer == 2) {
    // ============ GRU0: x-part = h1_t, h-part = h2_{t-1} ============
    bfrag gxf[3][2], ghf[3][2];
    facc brz4[2], bnx4, bnh4;
    #pragma unroll
    for (int G = 0; G < 3; ++G) {
      const float sc = (G == 2) ? ST2 : SS;
      const int col = G * 64 + lo4 * 16 + lc;
      #pragma unroll
      for (int kt = 0; kt < 2; ++kt) {
        bfrag f0, f1;
        #pragma unroll
        for (int j = 0; j < 8; ++j) {
          const int o = col * 64 + kt * 32 + kb + j;
          f0[j] = f2bf(sc * gw_ih0[o]);
          f1[j] = f2bf(sc * gw_hh0[o]);
        }
        gxf[G][kt] = f0; ghf[G][kt] = f1;
      }
      if (G < 2) brz4[G] = bcast4(sc * (gb_ih0[col] + gb_hh0[col]));
      else { bnx4 = bcast4(sc * gb_ih0[col]); bnh4 = bcast4(sc * gb_hh0[col]); }
    }
    float h2[2] = {0.f, 0.f};
    for (int tb = 0; tb < TT / 4; ++tb) {
      #pragma unroll
      for (int u = 0; u < 4; ++u) {
        const int t = tb * 4 + u;
        spin_grp(F1, t + 1);                         // h1[t] ready (early)
        const short* sx = S1 + u * SLOT;
        const bfrag ax0 = *(const bfrag*)(sx + lc * SR + kb);
        const bfrag ax1 = *(const bfrag*)(sx + lc * SR + 32 + kb);
        facc rz[2], axn;
        #pragma unroll
        for (int G = 0; G < 2; ++G) {                // x-part off critical path
          facc z = MFMA(ax0, gxf[G][0], brz4[G]);
          z = MFMA(ax1, gxf[G][1], z);
          rz[G] = z;
        }
        axn = MFMA(ax0, gxf[2][0], bnx4);
        axn = MFMA(ax1, gxf[2][1], axn);
        if (tb >= 1) spin_grp(F3, t - 3);            // GRU1 freed slot
        if (tb > 0 || u > 0) spin_grp(F2, t);        // own group done t-1
        const short* sh = S2 + ((u + 3) & 3) * SLOT;
        const bfrag ah0 = *(const bfrag*)(sh + lc * SR + kb);
        const bfrag ah1 = *(const bfrag*)(sh + lc * SR + 32 + kb);
        facc ahn = MFMA(ah0, ghf[2][0], bnh4);
        ahn = MFMA(ah1, ghf[2][1], ahn);
        #pragma unroll
        for (int G = 0; G < 2; ++G) {
          rz[G] = MFMA(ah0, ghf[G][0], rz[G]);
          rz[G] = MFMA(ah1, ghf[G][1], rz[G]);
        }
        float hh[2];
        #pragma unroll
        for (int m = 0; m < 2; ++m) {
          const float r_ = sigmP(rz[0][m]);
          const float z_ = sigmP(rz[1][m]);
          const float n_ = tanhP(axn[m] + r_ * ahn[m]);
          h2[m] = n_ + z_ * (h2[m] - n_);
          hh[m] = h2[m];
        }
        const unsigned pk = pk_bf16(hh[0], hh[1]);
        short* d = S2 + u * SLOT;
        d[wrbase]      = (short)pk;
        d[wrbase + SR] = (short)(pk >> 16);
        __threadfence_block();
        if (l == 0) F2[lo4] = t + 1;
      }
    }
  } else {
    // ============ GRU1: x-part = h2_t, h-part = h3_{t-1} ============
    bfrag gxf[3][2], ghf[3][2];
    facc brz4[2], bnx4, bnh4;
    #pragma unroll
    for (int G = 0; G < 3; ++G) {
      const float sc = (G == 2) ? ST2 : SS;
      const int col = G * 64 + lo4 * 16 + lc;
      #pragma unroll
      for (int kt = 0; kt < 2; ++kt) {
        bfrag f0, f1;
        #pragma unroll
        for (int j = 0; j < 8; ++j) {
          const int o = col * 64 + kt * 32 + kb + j;
          f0[j] = f2bf(sc * gw_ih1[o]);
          f1[j] = f2bf(sc * gw_hh1[o]);
        }
        gxf[G][kt] = f0; ghf[G][kt] = f1;
      }
      if (G < 2) brz4[G] = bcast4(sc * (gb_ih1[col] + gb_hh1[col]));
      else { bnx4 = bcast4(sc * gb_ih1[col]); bnh4 = bcast4(sc * gb_hh1[col]); }
    }
    float h3[2] = {0.f, 0.f};
    for (int tb = 0; tb < TT / 4; ++tb) {
      #pragma unroll
      for (int u = 0; u < 4; ++u) {
        const int t = tb * 4 + u;
        spin_grp(F2, t + 1);                         // h2[t] ready (early)
        const short* sx = S2 + u * SLOT;
        const bfrag ax0 = *(const bfrag*)(sx + lc * SR + kb);
        const bfrag ax1 = *(const bfrag*)(sx + lc * SR + 32 + kb);
        facc rz[2], axn;
        #pragma unroll
        for (int G = 0; G < 2; ++G) {
          facc z = MFMA(ax0, gxf[G][0], brz4[G]);
          z = MFMA(ax1, gxf[G][1], z);
          rz[G] = z;
        }
        axn = MFMA(ax0, gxf[2][0], bnx4);
        axn = MFMA(ax1, gxf[2][1], axn);
        if (tb > 0 || u > 0) spin_grp(F3, t);        // own group done t-1
        const short* sh = S3 + ((u + 3) & 3) * SLOT;
        const bfrag ah0 = *(const bfrag*)(sh + lc * SR + kb);
        const bfrag ah1 = *(const bfrag*)(sh + lc * SR + 32 + kb);
        facc ahn = MFMA(ah0, ghf[2][0], bnh4);
        ahn = MFMA(ah1, ghf[2][1], ahn);
        #pragma unroll
        for (int G = 0; G < 2; ++G) {
          rz[G] = MFMA(ah0, ghf[G][0], rz[G]);
          rz[G] = MFMA(ah1, ghf[G][1], rz[G]);
        }
        float hh[2];
        #pragma unroll
        for (int m = 0; m < 2; ++m) {
          const float r_ = sigmP(rz[0][m]);
          const float z_ = sigmP(rz[1][m]);
          const float n_ = tanhP(axn[m] + r_ * ahn[m]);
          h3[m] = n_ + z_ * (h3[m] - n_);
          hh[m] = h3[m];
        }
        const unsigned pk = pk_bf16(hh[0], hh[1]);
        short* d = S3 + u * SLOT;
        d[wrbase]      = (short)pk;
        d[wrbase + SR] = (short)(pk >> 16);
        __threadfence_block();
        if (l == 0) F3[lo4] = t + 1;
      }
    }
    // final hidden state -> hfin (batch rows 2lq, 2lq+1)
    #pragma unroll
    for (int m = 0; m < 2; ++m)
      hfin[2 * lq + m][lo4 * 16 + lc] = h3[m];
  }

  __syncthreads();
  if (tid < 8) {
    float s = fc_b[0];
    #pragma unroll 8
    for (int d = 0; d < 64; ++d) s += hfin[tid][d] * fc_w[d];
    out[rb0 + tid] = s;
  }
}

extern "C" void kernel_launch(void* const* d_in, const int* in_sizes, int n_in,
                              void* d_out, int out_size, void* d_ws, size_t ws_size,
                              hipStream_t stream) {
  const float* x      = (const float*)d_in[0];
  const float* lw_ih0 = (const float*)d_in[1];
  const float* lw_hh0 = (const float*)d_in[2];
  const float* lb_ih0 = (const float*)d_in[3];
  const float* lb_hh0 = (const float*)d_in[4];
  const float* lw_ih1 = (const float*)d_in[5];
  const float* lw_hh1 = (const float*)d_in[6];
  const float* lb_ih1 = (const float*)d_in[7];
  const float* lb_hh1 = (const float*)d_in[8];
  const float* gw_ih0 = (const float*)d_in[9];
  const float* gw_hh0 = (const float*)d_in[10];
  const float* gb_ih0 = (const float*)d_in[11];
  const float* gb_hh0 = (const float*)d_in[12];
  const float* gw_ih1 = (const float*)d_in[13];
  const float* gw_hh1 = (const float*)d_in[14];
  const float* gb_ih1 = (const float*)d_in[15];
  const float* gb_hh1 = (const float*)d_in[16];
  const float* fc_w   = (const float*)d_in[17];
  const float* fc_b   = (const float*)d_in[18];

  rnn_fused<<<dim3(2048 / 8), dim3(1024), 0, stream>>>(
      x, lw_ih0, lw_hh0, lb_ih0, lb_hh0, lw_ih1, lw_hh1, lb_ih1, lb_hh1,
      gw_ih0, gw_hh0, gb_ih0, gb_hh0, gw_ih1, gw_hh1, gb_ih1, gb_hh1,
      fc_w, fc_b, (float*)d_out);
}

// Round 13
// 381.001 us; speedup vs baseline: 1.4223x; 1.4223x over previous
//
#include <hip/hip_runtime.h>

// Fused 4-layer RNN (LSTM,LSTM,GRU,GRU, H=64) + FC head. B=2048, T=512.
// ELASTIC layer pipeline with LDS counter sync (R10 mechanism: atomicAdd
// counters + s_sleep spin): 256 blocks x 1024 threads (16 waves). Layer L
// owns waves [4L,4L+4); each wave owns a 16-dim h-chunk. 8 batch rows per
// block at A-rows {0,1,4,5,8,9,12,13} -> each lane owns rows m={0,1}.
// Each stream is a 4-deep LDS ring; monotonic counters cnt[4] gate
// consumers + back-pressure. R13 (only delta vs R10): tick reordered for
// layers 1-3 -> upstream spin + upstream reads + x-part MFMAs run BEFORE
// the back-pressure/own-group spins; only h-part MFMA + elementwise sit on
// the post-spin critical path. Bias folded into MFMA C operand; weights
// pre-scaled by -log2e / -2log2e (exp2-native activations).

#define TT 512
#define SR 72            // state row stride (shorts)
#define SLOT (16 * SR)   // one ring slot (shorts)
#define LOG2E 1.44269504f

typedef __attribute__((ext_vector_type(8))) short bfrag;  // 8 bf16
typedef __attribute__((ext_vector_type(4))) float facc;   // 4 f32

#define MFMA(a,b,c) __builtin_amdgcn_mfma_f32_16x16x32_bf16((a),(b),(c),0,0,0)

__device__ __forceinline__ short f2bf(float f){
  union { float f; unsigned u; } v; v.f = f;
  return (short)((v.u + 0x7fffu + ((v.u >> 16) & 1u)) >> 16);  // RNE
}
// u already scaled by -log2e: sigma(x) = 1/(1+2^u)
__device__ __forceinline__ float sigmP(float u){
  return __builtin_amdgcn_rcpf(1.0f + __builtin_amdgcn_exp2f(u));
}
// u already scaled by -2*log2e: tanh(x) = 2/(1+2^u) - 1
__device__ __forceinline__ float tanhP(float u){
  return 2.0f * __builtin_amdgcn_rcpf(1.0f + __builtin_amdgcn_exp2f(u)) - 1.0f;
}
__device__ __forceinline__ void spin_ge(volatile int* p, int tgt){
  if (*p >= tgt) return;
  do { __builtin_amdgcn_s_sleep(1); } while (*p < tgt);
}
__device__ __forceinline__ facc bcast4(float v){
  facc b; b[0] = v; b[1] = v; b[2] = v; b[3] = v; return b;
}

__global__ __launch_bounds__(1024) void rnn_fused(
    const float* __restrict__ x,
    const float* __restrict__ lw_ih0, const float* __restrict__ lw_hh0,
    const float* __restrict__ lb_ih0, const float* __restrict__ lb_hh0,
    const float* __restrict__ lw_ih1, const float* __restrict__ lw_hh1,
    const float* __restrict__ lb_ih1, const float* __restrict__ lb_hh1,
    const float* __restrict__ gw_ih0, const float* __restrict__ gw_hh0,
    const float* __restrict__ gb_ih0, const float* __restrict__ gb_hh0,
    const float* __restrict__ gw_ih1, const float* __restrict__ gw_hh1,
    const float* __restrict__ gb_ih1, const float* __restrict__ gb_hh1,
    const float* __restrict__ fc_w, const float* __restrict__ fc_b,
    float* __restrict__ out)
{
  __shared__ __align__(16) short S0[4 * SLOT];  // h0 ring
  __shared__ __align__(16) short S1[4 * SLOT];  // h1 ring
  __shared__ __align__(16) short S2[4 * SLOT];  // h2 ring
  __shared__ __align__(16) short S3[4 * SLOT];  // h3 ring
  __shared__ float xs[8][TT];                   // full x for our 8 rows
  __shared__ float hfin[8][68];
  __shared__ int cnt[4];

  const int tid = threadIdx.x;
  const int w     = tid >> 6;      // wave 0..15
  const int layer = w >> 2;        // 0..3
  const int lo4   = w & 3;         // h-chunk [lo4*16, lo4*16+16)
  const int l   = tid & 63;
  const int lq  = l >> 4;          // lane owns batch rows 2lq, 2lq+1
  const int lc  = l & 15;
  const int kb  = lq * 8;
  const int rb0 = blockIdx.x * 8;
  const int wrbase = (4 * lq) * SR + lo4 * 16 + lc;   // + m*SR
  volatile int* vc = cnt;

  const float SS  = -LOG2E;          // sigmoid-gate scale
  const float ST2 = -2.0f * LOG2E;   // tanh-gate scale

  // preload all 512 timesteps of x for our 8 rows (4096 floats, 4/thread)
  {
    const int idx = tid * 4;
    const int row = idx >> 9, t0 = idx & 511;
    *(float4*)&xs[row][t0] = *(const float4*)(x + (rb0 + row) * TT + t0);
  }
  for (int i = tid; i < 4 * SLOT; i += 1024) {
    S0[i] = 0; S1[i] = 0; S2[i] = 0; S3[i] = 0;
  }
  if (tid < 4) cnt[tid] = 0;
  __syncthreads();

  if (layer == 0) {
    // ============ LSTM0: K=64 (h-part; x is scalar FMA) ============
    bfrag wf[4][2];
    float wxs[4];
    facc b4[4];
    #pragma unroll
    for (int G = 0; G < 4; ++G) {
      const float sc = (G == 2) ? ST2 : SS;
      const int col = G * 64 + lo4 * 16 + lc;
      #pragma unroll
      for (int kt = 0; kt < 2; ++kt) {
        bfrag f;
        #pragma unroll
        for (int j = 0; j < 8; ++j)
          f[j] = f2bf(sc * lw_hh0[col * 64 + kt * 32 + kb + j]);
        wf[G][kt] = f;
      }
      wxs[G] = sc * lw_ih0[col];
      b4[G]  = bcast4(sc * (lb_ih0[col] + lb_hh0[col]));
    }
    float c0[2] = {0.f, 0.f};
    #pragma unroll 2
    for (int t = 0; t < TT; ++t) {
      if (t >= 4) spin_ge(vc + 1, 4 * (t - 3));   // LSTM1 freed slot t&3
      if (t >= 1) spin_ge(vc + 0, 4 * t);         // own group done t-1
      __threadfence_block();
      const short* s = S0 + ((t - 1) & 3) * SLOT;
      const bfrag a0 = *(const bfrag*)(s + lc * SR + kb);
      const bfrag a1 = *(const bfrag*)(s + lc * SR + 32 + kb);
      facc acc[4];
      #pragma unroll
      for (int G = 0; G < 4; ++G) {
        facc z = MFMA(a0, wf[G][0], b4[G]);
        z = MFMA(a1, wf[G][1], z);
        acc[G] = z;
      }
      short* d = S0 + (t & 3) * SLOT;
      #pragma unroll
      for (int m = 0; m < 2; ++m) {
        const float xv = xs[2 * lq + m][t];
        const float i_ = sigmP(acc[0][m] + xv * wxs[0]);
        const float f_ = sigmP(acc[1][m] + xv * wxs[1]);
        const float g_ = tanhP(acc[2][m] + xv * wxs[2]);
        const float o_ = sigmP(acc[3][m] + xv * wxs[3]);
        c0[m] = f_ * c0[m] + i_ * g_;
        d[wrbase + m * SR] = f2bf(o_ * tanhP(c0[m] * ST2));
      }
      __threadfence_block();
      if (l == 0) atomicAdd(&cnt[0], 1);
    }
  } else if (layer == 1) {
    // ============ LSTM1: K=128 ([h0_t | h1_{t-1}]) ============
    bfrag wxf[4][2], whf[4][2];
    facc b4[4];
    #pragma unroll
    for (int G = 0; G < 4; ++G) {
      const float sc = (G == 2) ? ST2 : SS;
      const int col = G * 64 + lo4 * 16 + lc;
      #pragma unroll
      for (int kt = 0; kt < 2; ++kt) {
        bfrag f0, f1;
        #pragma unroll
        for (int j = 0; j < 8; ++j) {
          const int o = col * 64 + kt * 32 + kb + j;
          f0[j] = f2bf(sc * lw_ih1[o]);
          f1[j] = f2bf(sc * lw_hh1[o]);
        }
        wxf[G][kt] = f0; whf[G][kt] = f1;
      }
      b4[G] = bcast4(sc * (lb_ih1[col] + lb_hh1[col]));
    }
    float c1[2] = {0.f, 0.f};
    #pragma unroll 2
    for (int t = 0; t < TT; ++t) {
      spin_ge(vc + 0, 4 * (t + 1));               // h0[t] ready (early)
      __threadfence_block();
      const short* sx = S0 + (t & 3) * SLOT;
      const bfrag ax0 = *(const bfrag*)(sx + lc * SR + kb);
      const bfrag ax1 = *(const bfrag*)(sx + lc * SR + 32 + kb);
      facc acc[4];
      #pragma unroll
      for (int G = 0; G < 4; ++G) {               // x-part off critical path
        facc z = MFMA(ax0, wxf[G][0], b4[G]);
        z = MFMA(ax1, wxf[G][1], z);
        acc[G] = z;
      }
      if (t >= 4) spin_ge(vc + 2, 4 * (t - 3));   // GRU0 freed slot
      if (t >= 1) spin_ge(vc + 1, 4 * t);         // own group done t-1
      __threadfence_block();
      const short* sh = S1 + ((t - 1) & 3) * SLOT;
      const bfrag ah0 = *(const bfrag*)(sh + lc * SR + kb);
      const bfrag ah1 = *(const bfrag*)(sh + lc * SR + 32 + kb);
      #pragma unroll
      for (int G = 0; G < 4; ++G) {
        acc[G] = MFMA(ah0, whf[G][0], acc[G]);
        acc[G] = MFMA(ah1, whf[G][1], acc[G]);
      }
      short* d = S1 + (t & 3) * SLOT;
      #pragma unroll
      for (int m = 0; m < 2; ++m) {
        const float i_ = sigmP(acc[0][m]);
        const float f_ = sigmP(acc[1][m]);
        const float g_ = tanhP(acc[2][m]);
        const float o_ = sigmP(acc[3][m]);
        c1[m] = f_ * c1[m] + i_ * g_;
        d[wrbase + m * SR] = f2bf(o_ * tanhP(c1[m] * ST2));
      }
      __threadfence_block();
      if (l == 0) atomicAdd(&cnt[1], 1);
    }
  } else if (layer == 2) {
    // ============ GRU0: x-part = h1_t, h-part = h2_{t-1} ============
    bfrag gxf[3][2], ghf[3][2];
    facc brz4[2], bnx4, bnh4;
    #pragma unroll
    for (int G = 0; G < 3; ++G) {
      const float sc = (G == 2) ? ST2 : SS;
      const int col = G * 64 + lo4 * 16 + lc;
      #pragma unroll
      for (int kt = 0; kt < 2; ++kt) {
        bfrag f0, f1;
        #pragma unroll
        for (int j = 0; j < 8; ++j) {
          const int o = col * 64 + kt * 32 + kb + j;
          f0[j] = f2bf(sc * gw_ih0[o]);
          f1[j] = f2bf(sc * gw_hh0[o]);
        }
        gxf[G][kt] = f0; ghf[G][kt] = f1;
      }
      if (G < 2) brz4[G] = bcast4(sc * (gb_ih0[col] + gb_hh0[col]));
      else { bnx4 = bcast4(sc * gb_ih0[col]); bnh4 = bcast4(sc * gb_hh0[col]); }
    }
    float h2[2] = {0.f, 0.f};
    #pragma unroll 2
    for (int t = 0; t < TT; ++t) {
      spin_ge(vc + 1, 4 * (t + 1));               // h1[t] ready (early)
      __threadfence_block();
      const short* sx = S1 + (t & 3) * SLOT;
      const bfrag ax0 = *(const bfrag*)(sx + lc * SR + kb);
      const bfrag ax1 = *(const bfrag*)(sx + lc * SR + 32 + kb);
      facc rz[2], axn;
      #pragma unroll
      for (int G = 0; G < 2; ++G) {               // x-part off critical path
        facc z = MFMA(ax0, gxf[G][0], brz4[G]);
        z = MFMA(ax1, gxf[G][1], z);
        rz[G] = z;
      }
      axn = MFMA(ax0, gxf[2][0], bnx4);
      axn = MFMA(ax1, gxf[2][1], axn);
      if (t >= 4) spin_ge(vc + 3, 4 * (t - 3));   // GRU1 freed slot
      if (t >= 1) spin_ge(vc + 2, 4 * t);         // own group done t-1
      __threadfence_block();
      const short* sh = S2 + ((t - 1) & 3) * SLOT;
      const bfrag ah0 = *(const bfrag*)(sh + lc * SR + kb);
      const bfrag ah1 = *(const bfrag*)(sh + lc * SR + 32 + kb);
      facc ahn = MFMA(ah0, ghf[2][0], bnh4);
      ahn = MFMA(ah1, ghf[2][1], ahn);
      #pragma unroll
      for (int G = 0; G < 2; ++G) {
        rz[G] = MFMA(ah0, ghf[G][0], rz[G]);
        rz[G] = MFMA(ah1, ghf[G][1], rz[G]);
      }
      short* d = S2 + (t & 3) * SLOT;
      #pragma unroll
      for (int m = 0; m < 2; ++m) {
        const float r_ = sigmP(rz[0][m]);
        const float z_ = sigmP(rz[1][m]);
        const float n_ = tanhP(axn[m] + r_ * ahn[m]);
        h2[m] = n_ + z_ * (h2[m] - n_);
        d[wrbase + m * SR] = f2bf(h2[m]);
      }
      __threadfence_block();
      if (l == 0) atomicAdd(&cnt[2], 1);
    }
  } else {
    // ============ GRU1: x-part = h2_t, h-part = h3_{t-1} ============
    bfrag gxf[3][2], ghf[3][2];
    facc brz4[2], bnx4, bnh4;
    #pragma unroll
    for (int G = 0; G < 3; ++G) {
      const float sc = (G == 2) ? ST2 : SS;
      const int col = G * 64 + lo4 * 16 + lc;
      #pragma unroll
      for (int kt = 0; kt < 2; ++kt) {
        bfrag f0, f1;
        #pragma unroll
        for (int j = 0; j < 8; ++j) {
          const int o = col * 64 + kt * 32 + kb + j;
          f0[j] = f2bf(sc * gw_ih1[o]);
          f1[j] = f2bf(sc * gw_hh1[o]);
        }
        gxf[G][kt] = f0; ghf[G][kt] = f1;
      }
      if (G < 2) brz4[G] = bcast4(sc * (gb_ih1[col] + gb_hh1[col]));
      else { bnx4 = bcast4(sc * gb_ih1[col]); bnh4 = bcast4(sc * gb_hh1[col]); }
    }
    float h3[2] = {0.f, 0.f};
    #pragma unroll 2
    for (int t = 0; t < TT; ++t) {
      spin_ge(vc + 2, 4 * (t + 1));               // h2[t] ready (early)
      __threadfence_block();
      const short* sx = S2 + (t & 3) * SLOT;
      const bfrag ax0 = *(const bfrag*)(sx + lc * SR + kb);
      const bfrag ax1 = *(const bfrag*)(sx + lc * SR + 32 + kb);
      facc rz[2], axn;
      #pragma unroll
      for (int G = 0; G < 2; ++G) {
        facc z = MFMA(ax0, gxf[G][0], brz4[G]);
        z = MFMA(ax1, gxf[G][1], z);
        rz[G] = z;
      }
      axn = MFMA(ax0, gxf[2][0], bnx4);
      axn = MFMA(ax1, gxf[2][1], axn);
      if (t >= 1) spin_ge(vc + 3, 4 * t);         // own group done t-1
      __threadfence_block();
      const short* sh = S3 + ((t - 1) & 3) * SLOT;
      const bfrag ah0 = *(const bfrag*)(sh + lc * SR + kb);
      const bfrag ah1 = *(const bfrag*)(sh + lc * SR + 32 + kb);
      facc ahn = MFMA(ah0, ghf[2][0], bnh4);
      ahn = MFMA(ah1, ghf[2][1], ahn);
      #pragma unroll
      for (int G = 0; G < 2; ++G) {
        rz[G] = MFMA(ah0, ghf[G][0], rz[G]);
        rz[G] = MFMA(ah1, ghf[G][1], rz[G]);
      }
      short* d = S3 + (t & 3) * SLOT;
      #pragma unroll
      for (int m = 0; m < 2; ++m) {
        const float r_ = sigmP(rz[0][m]);
        const float z_ = sigmP(rz[1][m]);
        const float n_ = tanhP(axn[m] + r_ * ahn[m]);
        h3[m] = n_ + z_ * (h3[m] - n_);
        d[wrbase + m * SR] = f2bf(h3[m]);
      }
      __threadfence_block();
      if (l == 0) atomicAdd(&cnt[3], 1);
    }
    // final hidden state -> hfin (batch rows 2lq, 2lq+1)
    #pragma unroll
    for (int m = 0; m < 2; ++m)
      hfin[2 * lq + m][lo4 * 16 + lc] = h3[m];
  }

  __syncthreads();
  if (tid < 8) {
    float s = fc_b[0];
    #pragma unroll 8
    for (int d = 0; d < 64; ++d) s += hfin[tid][d] * fc_w[d];
    out[rb0 + tid] = s;
  }
}

extern "C" void kernel_launch(void* const* d_in, const int* in_sizes, int n_in,
                              void* d_out, int out_size, void* d_ws, size_t ws_size,
                              hipStream_t stream) {
  const float* x      = (const float*)d_in[0];
  const float* lw_ih0 = (const float*)d_in[1];
  const float* lw_hh0 = (const float*)d_in[2];
  const float* lb_ih0 = (const float*)d_in[3];
  const float* lb_hh0 = (const float*)d_in[4];
  const float* lw_ih1 = (const float*)d_in[5];
  const float* lw_hh1 = (const float*)d_in[6];
  const float* lb_ih1 = (const float*)d_in[7];
  const float* lb_hh1 = (const float*)d_in[8];
  const float* gw_ih0 = (const float*)d_in[9];
  const float* gw_hh0 = (const float*)d_in[10];
  const float* gb_ih0 = (const float*)d_in[11];
  const float* gb_hh0 = (const float*)d_in[12];
  const float* gw_ih1 = (const float*)d_in[13];
  const float* gw_hh1 = (const float*)d_in[14];
  const float* gb_ih1 = (const float*)d_in[15];
  const float* gb_hh1 = (const float*)d_in[16];
  const float* fc_w   = (const float*)d_in[17];
  const float* fc_b   = (const float*)d_in[18];

  rnn_fused<<<dim3(2048 / 8), dim3(1024), 0, stream>>>(
      x, lw_ih0, lw_hh0, lb_ih0, lb_hh0, lw_ih1, lw_hh1, lb_ih1, lb_hh1,
      gw_ih0, gw_hh0, gb_ih0, gb_hh0, gw_ih1, gw_hh1, gb_ih1, gb_hh1,
      fc_w, fc_b, (float*)d_out);
}